// Round 2
// baseline (101.968 us; speedup 1.0000x reference)
//
#include <hip/hip_runtime.h>
#include <hip/hip_cooperative_groups.h>

namespace cg = cooperative_groups;

// CrossModalCenterLoss collapses analytically:
//   mask = one_hot(labels) -> only distmat[b, labels[b]] survives the product;
//   clip(0, 1e-12, 1e12) = 1e-12 for the B*(C-1) masked-out zeros.
//   loss = mean_b clip(||x_b - centers[l_b]||^2) + (C-1)*1e-12
// Traffic: x 4 MB + gathered centers <=10 MB + labels 16 KB  (~2.3 us @ 6.3 TB/s).
// Measurement floor is harness reset (256 MB ws poison ~44 us) — we minimize
// our slice: ONE cooperative dispatch, grid.sync between row-dist and reduce.

#define BATCH       4096
#define FEAT_DIM    256
#define NUM_CLS     10000
#define CLAMP_MIN_F 1e-12f
#define CLAMP_MAX_F 1e12f

// 256 blocks (1/CU) x 256 threads; each block: 16 rows (4 waves x 4 rows).
__global__ __launch_bounds__(256) void cmcl_fused(
    const float* __restrict__ x,
    const int*   __restrict__ labels,
    const float* __restrict__ centers,
    float*       __restrict__ partial,   // [256] floats in d_ws
    float*       __restrict__ out)
{
    const int lane = threadIdx.x & 63;
    const int wave = threadIdx.x >> 6;

    float acc = 0.0f;   // lane-0-of-wave accumulator of clamped row distances

    #pragma unroll
    for (int i = 0; i < 4; ++i) {
        const int row   = (blockIdx.x << 4) + (wave << 2) + i;   // < 4096
        const int label = labels[row];

        // 64 lanes * float4 = 256 floats = one full row, coalesced.
        float4 xv = ((const float4*)(x       + (size_t)row   * FEAT_DIM))[lane];
        float4 cv = ((const float4*)(centers + (size_t)label * FEAT_DIM))[lane];
        float dx = xv.x - cv.x;
        float dy = xv.y - cv.y;
        float dz = xv.z - cv.z;
        float dw = xv.w - cv.w;
        float v = dx*dx + dy*dy + dz*dz + dw*dw;

        #pragma unroll
        for (int off = 32; off > 0; off >>= 1)
            v += __shfl_down(v, off, 64);

        if (lane == 0)
            acc += fminf(fmaxf(v, CLAMP_MIN_F), CLAMP_MAX_F);  // clamp per row
    }

    __shared__ float sm[4];
    if (lane == 0) sm[wave] = acc;
    __syncthreads();
    if (threadIdx.x == 0)
        partial[blockIdx.x] = sm[0] + sm[1] + sm[2] + sm[3];

    cg::this_grid().sync();

    // Block 0 reduces the 256 partials deterministically.
    if (blockIdx.x == 0) {
        float v = partial[threadIdx.x];
        #pragma unroll
        for (int off = 32; off > 0; off >>= 1)
            v += __shfl_down(v, off, 64);

        __shared__ float sm2[4];
        if (lane == 0) sm2[wave] = v;
        __syncthreads();
        if (threadIdx.x == 0) {
            float total = sm2[0] + sm2[1] + sm2[2] + sm2[3];
            out[0] = total / (float)BATCH + (float)(NUM_CLS - 1) * CLAMP_MIN_F;
        }
    }
}

extern "C" void kernel_launch(void* const* d_in, const int* in_sizes, int n_in,
                              void* d_out, int out_size, void* d_ws, size_t ws_size,
                              hipStream_t stream) {
    const float* x       = (const float*)d_in[0];
    const int*   labels  = (const int*)  d_in[1];
    const float* centers = (const float*)d_in[2];
    float*       out     = (float*)d_out;
    float*       partial = (float*)d_ws;   // 256 floats = 1 KB of scratch

    void* args[] = { (void*)&x, (void*)&labels, (void*)&centers,
                     (void*)&partial, (void*)&out };
    hipLaunchCooperativeKernel((void*)cmcl_fused, dim3(256), dim3(256),
                               args, 0, stream);
}

// Round 3
// 66.661 us; speedup vs baseline: 1.5296x; 1.5296x over previous
//
#include <hip/hip_runtime.h>

// CrossModalCenterLoss collapses analytically:
//   mask = one_hot(labels) -> only distmat[b, labels[b]] survives the product;
//   clip(0, 1e-12, 1e12) contributes 1e-12 for each of the B*(C-1) masked zeros.
//   loss = mean_b clip(||x_b - centers[l_b]||^2, 1e-12, 1e12) + (C-1)*1e-12
//
// Traffic: x 4 MB + gathered centers <=10 MB + labels 16 KB (~2.3 us @ 6.3 TB/s).
// Measured floor is harness reset (256 MB ws poison fill ~42 us + restores).
// R2 showed hipLaunchCooperativeKernel costs +36 us/replay -> use ONE plain
// dispatch with a flag-based device-scope completion protocol instead:
// every block release-stores partial+MAGIC flag; block 0 acquire-spins on all
// 256 flags, then reduces deterministically. No scratch init required, so the
// 0xAA ws poison (or 0 on the correctness call) is harmless.

#define BATCH       4096
#define FEAT_DIM    256
#define NUM_CLS     10000
#define CLAMP_MIN_F 1e-12f
#define CLAMP_MAX_F 1e12f
#define NBLK        256
#define FLAG_MAGIC  0x13579BDFu

__global__ __launch_bounds__(256) void cmcl_onepass(
    const float* __restrict__ x,
    const int*   __restrict__ labels,
    const float* __restrict__ centers,
    float*       __restrict__ partial,    // d_ws + 0      : NBLK floats
    unsigned*    __restrict__ flags,      // d_ws + 1024 B : NBLK u32
    float*       __restrict__ out)
{
    const int lane = threadIdx.x & 63;
    const int wave = threadIdx.x >> 6;

    float acc = 0.0f;   // lane-0 accumulator of clamped row distances

    #pragma unroll
    for (int i = 0; i < 4; ++i) {
        const int row   = (blockIdx.x << 4) + (wave << 2) + i;   // < 4096
        const int label = labels[row];

        // 64 lanes * float4 = 256 floats = one full row, fully coalesced.
        float4 xv = ((const float4*)(x       + (size_t)row   * FEAT_DIM))[lane];
        float4 cv = ((const float4*)(centers + (size_t)label * FEAT_DIM))[lane];
        float dx = xv.x - cv.x;
        float dy = xv.y - cv.y;
        float dz = xv.z - cv.z;
        float dw = xv.w - cv.w;
        float v = dx*dx + dy*dy + dz*dz + dw*dw;

        #pragma unroll
        for (int off = 32; off > 0; off >>= 1)
            v += __shfl_down(v, off, 64);

        if (lane == 0)
            acc += fminf(fmaxf(v, CLAMP_MIN_F), CLAMP_MAX_F);  // clamp per row
    }

    __shared__ float sm[4];
    if (lane == 0) sm[wave] = acc;
    __syncthreads();

    if (threadIdx.x == 0) {
        partial[blockIdx.x] = sm[0] + sm[1] + sm[2] + sm[3];
        // Release-publish: partial store ordered before flag store, device scope.
        __hip_atomic_store(&flags[blockIdx.x], FLAG_MAGIC,
                           __ATOMIC_RELEASE, __HIP_MEMORY_SCOPE_AGENT);
    }

    // Final deterministic reduction by block 0 only.
    if (blockIdx.x != 0) return;

    // Each of the 256 threads waits for its flag (incl. our own, already set).
    while (__hip_atomic_load(&flags[threadIdx.x],
                             __ATOMIC_ACQUIRE, __HIP_MEMORY_SCOPE_AGENT)
           != FLAG_MAGIC) {
        __builtin_amdgcn_s_sleep(1);
    }
    __syncthreads();   // all 256 partials now visible

    float v = partial[threadIdx.x];
    #pragma unroll
    for (int off = 32; off > 0; off >>= 1)
        v += __shfl_down(v, off, 64);

    __shared__ float sm2[4];
    if (lane == 0) sm2[wave] = v;
    __syncthreads();
    if (threadIdx.x == 0) {
        float total = sm2[0] + sm2[1] + sm2[2] + sm2[3];
        out[0] = total / (float)BATCH + (float)(NUM_CLS - 1) * CLAMP_MIN_F;
    }
}

extern "C" void kernel_launch(void* const* d_in, const int* in_sizes, int n_in,
                              void* d_out, int out_size, void* d_ws, size_t ws_size,
                              hipStream_t stream) {
    const float* x       = (const float*)d_in[0];
    const int*   labels  = (const int*)  d_in[1];
    const float* centers = (const float*)d_in[2];
    float*       out     = (float*)d_out;
    float*       partial = (float*)d_ws;                      // 256 floats
    unsigned*    flags   = (unsigned*)((char*)d_ws + 1024);   // 256 u32

    cmcl_onepass<<<NBLK, 256, 0, stream>>>(x, labels, centers,
                                           partial, flags, out);
}